// Round 17
// baseline (139.231 us; speedup 1.0000x reference)
//
#include <hip/hip_runtime.h>
#include <hip/hip_bf16.h>
#include <math.h>

#define N_NODES 2000
#define DIN 256
#define DD 256
#define KTOP 10
#define CC 12
#define EG 64000
#define ET 50000
#define L1LEN 255
#define P1LEN 127
#define P2LEN 63
#define P3LEN 31
#define FLAT 2652
#define BN_INV 0.9999950000375f
#define CAP 96

typedef float v2 __attribute__((ext_vector_type(2)));
typedef __fp16 h2 __attribute__((ext_vector_type(2)));

__device__ __forceinline__ v2 v2fma(v2 a, v2 b, v2 c) {
#if __has_builtin(__builtin_elementwise_fma)
    return __builtin_elementwise_fma(a, b, c);
#else
    v2 r; r.x = fmaf(a.x, b.x, c.x); r.y = fmaf(a.y, b.y, c.y); return r;
#endif
}
__device__ __forceinline__ v2 sp(float s) { v2 r; r.x = s; r.y = s; return r; }

// ---- workspace layout (float offsets) ----
#define OFF_MEAN   0                          // 512000
#define OFF_H      512000                     // 512000
#define OFF_SC     1024000                    // 2000 (zeroed by memset)
#define OFF_CNT    1026000                    // 2000 ints (zeroed by memset)
#define OFF_NBR    1028000                    // 2000*96 ints
#define OFF_TAB    1220000
#define OFF_C1Q    (OFF_TAB)                  // [12][256] pre-pool conv1 const (l'=255 pad 0)
#define OFF_V1P    (OFF_TAB + 3072)           // [12][128] dot weights for s1 (k=127 pad 0)
#define OFF_B2F    (OFF_TAB + 4944)           // 12
#define OFF_B3F    (OFF_TAB + 5244)           // 12
#define OFF_V2T    (OFF_TAB + 5256)           // [64][12]
#define OFF_V3T    (OFF_TAB + 6024)           // [32][12]
#define OFF_C0     (OFF_TAB + 6408)           // 1
#define OFF_W2H    (OFF_TAB + 6412)           // [o][i] h2 = 144 dwords
#define OFF_WAH    (OFF_TAB + 6556)           // [o] h2 = 12
#define OFF_WBH    (OFF_TAB + 6568)           // [o] h2 = 12
#define OFF_W3H    (OFF_TAB + 6580)           // [i][o] h2 = 144

// ---------------- k_fill: bucket fill (0-249) + v-split (250-260) + fold (261) + xWr GEMM (262-765) ----------------
__global__ void k_fill(const int* __restrict__ ei, const float* __restrict__ x,
                       const float* __restrict__ Wr,
                       const float* __restrict__ fc1w, const float* __restrict__ fc1b,
                       const float* __restrict__ fc2w, const float* __restrict__ fc2b,
                       const float* __restrict__ bn4g, const float* __restrict__ bn4b,
                       const float* __restrict__ c1w,
                       const float* __restrict__ c2w, const float* __restrict__ c2b,
                       const float* __restrict__ c3w, const float* __restrict__ c3b,
                       const float* __restrict__ bn1g,
                       const float* __restrict__ bn2g, const float* __restrict__ bn2b,
                       const float* __restrict__ bn3g, const float* __restrict__ bn3b,
                       float* __restrict__ W) {
    __shared__ float Xs[32][33], Brs[32][33];
    const int tid = threadIdx.x, bid = blockIdx.x;
    if (bid < 250) {
        int e = bid * 256 + tid;
        int* cnt = (int*)(W + OFF_CNT);
        int* nbr = (int*)(W + OFF_NBR);
        int dst = ei[EG + e], src = ei[e];
        int slot = atomicAdd(&cnt[dst], 1);
        nbr[dst * CAP + slot] = src;
        return;
    }
    if (bid < 261) {  // v = fc1_w^T (fc2_w * BN_INV * bn4_g) split into V1P / V2T / V3T
        int j = (bid - 250) * 256 + tid;
        if (j >= FLAT) return;
        float acc = 0.f;
        for (int k = 0; k < 128; ++k)
            acc += fc1w[k * FLAT + j] * (fc2w[k] * (BN_INV * bn4g[k]));
        int c = j / 221, pos = j - c * 221;
        if (pos < 127)      W[OFF_V1P + c * 128 + pos] = acc;
        else if (pos < 190) W[OFF_V2T + (pos - 127) * 12 + c] = acc;
        else                W[OFF_V3T + (pos - 190) * 12 + c] = acc;
        return;
    }
    if (bid == 261) {  // fold BN into conv weights (h2 tables) + pads
        if (tid < 144) {
            int o = tid / 12, i = tid - o * 12;
            float s2 = BN_INV * bn2g[i];
            ((h2*)(W + OFF_W2H))[o * 12 + i] =
                __builtin_amdgcn_cvt_pkrtz(c2w[o * 24 + i * 2] * s2, c2w[o * 24 + i * 2 + 1] * s2);
            float s3 = BN_INV * bn3g[i];
            ((h2*)(W + OFF_W3H))[i * 12 + o] =
                __builtin_amdgcn_cvt_pkrtz(c3w[o * 24 + i * 2] * s3, c3w[o * 24 + i * 2 + 1] * s3);
        }
        if (tid < 12) {
            float s2 = c2b[tid], s3 = c3b[tid];
            for (int i = 0; i < 12; ++i) {
                s2 += (c2w[tid * 24 + i * 2] + c2w[tid * 24 + i * 2 + 1]) * bn2b[i];
                s3 += (c3w[tid * 24 + i * 2] + c3w[tid * 24 + i * 2 + 1]) * bn3b[i];
            }
            W[OFF_B2F + tid] = s2;
            W[OFF_B3F + tid] = s3;
            W[OFF_V1P + tid * 128 + 127] = 0.f;   // pad: lane-63 rB dot weight
            float g0 = BN_INV * bn1g[0], g1 = BN_INV * bn1g[1];
            ((h2*)(W + OFF_WAH))[tid] =
                __builtin_amdgcn_cvt_pkrtz(c1w[tid * 24 + 0] * g0, c1w[tid * 24 + 1] * g0);
            ((h2*)(W + OFF_WBH))[tid] =
                __builtin_amdgcn_cvt_pkrtz(c1w[tid * 24 + 2] * g1, c1w[tid * 24 + 3] * g1);
        }
        if (tid == 0) {
            float c = fc2b[0];
            for (int k = 0; k < 128; ++k)
                c += fc2w[k] * (fc1b[k] * (BN_INV * bn4g[k]) + bn4b[k]);
            W[OFF_C0] = c;
        }
        return;
    }
    // ---- blocks 262..765: hpre = x @ Wr^T into OFF_H (no bias/relu) ----
    {
        int id = bid - 262;
        int bx = id & 7, by = id >> 3;
        int n0 = by * 32, d0 = bx * 32;
        int tx = tid & 15, ty = tid >> 4;
        int lrow = tid >> 3, lcol = (tid & 7) * 4;
        v2 acc0 = sp(0.f), acc1 = sp(0.f);
        for (int k0 = 0; k0 < DIN; k0 += 32) {
            int gn = n0 + lrow;
            float4 xv = (gn < N_NODES) ? *(const float4*)(x + gn * DIN + k0 + lcol)
                                       : make_float4(0.f, 0.f, 0.f, 0.f);
            Xs[lrow][lcol + 0] = xv.x; Xs[lrow][lcol + 1] = xv.y;
            Xs[lrow][lcol + 2] = xv.z; Xs[lrow][lcol + 3] = xv.w;
            float4 rv = *(const float4*)(Wr + (d0 + lrow) * DIN + k0 + lcol);
            Brs[lrow][lcol + 0] = rv.x; Brs[lrow][lcol + 1] = rv.y;
            Brs[lrow][lcol + 2] = rv.z; Brs[lrow][lcol + 3] = rv.w;
            __syncthreads();
#pragma unroll
            for (int kk = 0; kk < 32; ++kk) {
                v2 r; r.x = Brs[2 * tx][kk]; r.y = Brs[2 * tx + 1][kk];
                acc0 = v2fma(r, sp(Xs[2 * ty][kk]), acc0);
                acc1 = v2fma(r, sp(Xs[2 * ty + 1][kk]), acc1);
            }
            __syncthreads();
        }
        float* h = W + OFF_H;
#pragma unroll
        for (int i = 0; i < 2; ++i) {
            int n = n0 + 2 * ty + i;
            if (n < N_NODES) {
                v2 a = (i == 0) ? acc0 : acc1;
                h[n * DD + d0 + 2 * tx] = a.x;
                h[n * DD + d0 + 2 * tx + 1] = a.y;
            }
        }
    }
}

// ---------------- k_gather: 1 block/node; 4 waves = 2(neighbor half) x 2(feature half) ----------------
__global__ void k_gather(const float* __restrict__ x, float* __restrict__ W) {
    __shared__ float part[2][128];
    const int tid = threadIdx.x;
    const int w4 = tid >> 6, lane = tid & 63;
    const int half = w4 >> 1;       // neighbor half
    const int fh = w4 & 1;          // feature half
    const int n = blockIdx.x;
    const int* cnt = (const int*)(W + OFF_CNT);
    const int* nbr = (const int*)(W + OFF_NBR);
    int dg = cnt[n];
    int mid = dg >> 1;
    int j0 = half ? mid : 0;
    int j1 = half ? dg : mid;
    const int* row = nbr + n * CAP;
    const int fo = fh * 128 + lane * 2;
    float ax = 0.f, ay = 0.f;
    int j = j0;
    for (; j + 4 <= j1; j += 4) {
        int s0 = row[j], s1 = row[j + 1], s2 = row[j + 2], s3 = row[j + 3];
        float2 v0 = *(const float2*)(x + s0 * DIN + fo);
        float2 v1 = *(const float2*)(x + s1 * DIN + fo);
        float2 v2_ = *(const float2*)(x + s2 * DIN + fo);
        float2 v3 = *(const float2*)(x + s3 * DIN + fo);
        ax += v0.x + v1.x + v2_.x + v3.x;
        ay += v0.y + v1.y + v2_.y + v3.y;
    }
    for (; j < j1; ++j) {
        int s0 = row[j];
        float2 v0 = *(const float2*)(x + s0 * DIN + fo);
        ax += v0.x; ay += v0.y;
    }
    if (half == 1) {
        part[fh][lane * 2] = ax;
        part[fh][lane * 2 + 1] = ay;
    }
    __syncthreads();
    if (half == 0) {
        ax += part[fh][lane * 2];
        ay += part[fh][lane * 2 + 1];
        float rd = 1.0f / fmaxf((float)dg, 1.0f);
        float2 o2; o2.x = ax * rd; o2.y = ay * rd;
        *(float2*)(W + OFF_MEAN + n * DIN + fo) = o2;
    }
}

// ---------------- k_sage: h = relu(mean @ Wl^T + bl + hpre), fused score atomics ----------------
__global__ void k_sage(const float* __restrict__ Wl, const float* __restrict__ bl,
                       const float* __restrict__ tw, float* __restrict__ W) {
    __shared__ float As[32][33], Bls[32][33];
    const float* mean = W + OFF_MEAN;
    float* h = W + OFF_H;
    float* sc = W + OFF_SC;
    int tid = threadIdx.x;
    int tx = tid & 15, ty = tid >> 4;
    int n0 = blockIdx.y * 32, d0 = blockIdx.x * 32;
    int lrow = tid >> 3, lcol = (tid & 7) * 4;
    v2 acc0 = sp(0.f), acc1 = sp(0.f);
    for (int k0 = 0; k0 < DIN; k0 += 32) {
        int gn = n0 + lrow;
        float4 av = (gn < N_NODES) ? *(const float4*)(mean + gn * DIN + k0 + lcol)
                                   : make_float4(0.f, 0.f, 0.f, 0.f);
        As[lrow][lcol + 0] = av.x; As[lrow][lcol + 1] = av.y;
        As[lrow][lcol + 2] = av.z; As[lrow][lcol + 3] = av.w;
        float4 bv = *(const float4*)(Wl + (d0 + lrow) * DIN + k0 + lcol);
        Bls[lrow][lcol + 0] = bv.x; Bls[lrow][lcol + 1] = bv.y;
        Bls[lrow][lcol + 2] = bv.z; Bls[lrow][lcol + 3] = bv.w;
        __syncthreads();
#pragma unroll
        for (int kk = 0; kk < 32; ++kk) {
            v2 b; b.x = Bls[2 * tx][kk]; b.y = Bls[2 * tx + 1][kk];
            acc0 = v2fma(b, sp(As[2 * ty][kk]), acc0);
            acc1 = v2fma(b, sp(As[2 * ty + 1][kk]), acc1);
        }
        __syncthreads();
    }
    float tw0 = tw[d0 + 2 * tx], tw1 = tw[d0 + 2 * tx + 1];
    float bl0 = bl[d0 + 2 * tx], bl1 = bl[d0 + 2 * tx + 1];
    float s0 = 0.f, s1 = 0.f;
#pragma unroll
    for (int i = 0; i < 2; ++i) {
        int n = n0 + 2 * ty + i;
        if (n < N_NODES) {
            v2 a = (i == 0) ? acc0 : acc1;
            float h0 = fmaxf(a.x + bl0 + h[n * DD + d0 + 2 * tx], 0.f);
            float h1 = fmaxf(a.y + bl1 + h[n * DD + d0 + 2 * tx + 1], 0.f);
            h[n * DD + d0 + 2 * tx] = h0;
            h[n * DD + d0 + 2 * tx + 1] = h1;
            float s = fmaf(h0, tw0, h1 * tw1);
            if (i == 0) s0 = s; else s1 = s;
        }
    }
#pragma unroll
    for (int off = 8; off > 0; off >>= 1) {
        s0 += __shfl_xor(s0, off, 64);
        s1 += __shfl_xor(s1, off, 64);
    }
    if (tx == 0) {
        int n = n0 + 2 * ty;
        if (n < N_NODES) atomicAdd(&sc[n], s0);
        if (n + 1 < N_NODES) atomicAdd(&sc[n + 1], s1);
    }
}

// ---------------- k_topk: 12 blocks; wave-topk + one channel of pre-pool const C1Q ----------------
__global__ void k_topk(const float* __restrict__ tw, const float* __restrict__ c1w,
                       const float* __restrict__ c1b, const float* __restrict__ bn1g,
                       const float* __restrict__ bn1b, float* __restrict__ W) {
    __shared__ float s_tt[KTOP];
    __shared__ int   s_ti[KTOP];
    int tid = threadIdx.x;
    if (tid < 64) {
        int lane = tid;
        const float* sc = W + OFF_SC;
        float v[32];
#pragma unroll
        for (int s = 0; s < 32; ++s) {
            int idx = s * 64 + lane;
            v[s] = (idx < N_NODES) ? sc[idx] : -1e30f;
        }
        float p = 0.f;
#pragma unroll
        for (int k = 0; k < 4; ++k) { float t = tw[lane + 64 * k]; p = fmaf(t, t, p); }
#pragma unroll
        for (int off = 32; off > 0; off >>= 1) p += __shfl_xor(p, off, 64);
        float rnorm = 1.0f / sqrtf(p);
#pragma unroll
        for (int k = 0; k < KTOP; ++k) {
            float m = v[0];
#pragma unroll
            for (int s = 1; s < 32; ++s) m = fmaxf(m, v[s]);
#pragma unroll
            for (int off = 32; off > 0; off >>= 1) m = fmaxf(m, __shfl_xor(m, off, 64));
            int cand = 0x7fffffff;
#pragma unroll
            for (int s = 0; s < 32; ++s)
                if (v[s] == m) cand = min(cand, s * 64 + lane);
#pragma unroll
            for (int off = 32; off > 0; off >>= 1) cand = min(cand, __shfl_xor(cand, off, 64));
#pragma unroll
            for (int s = 0; s < 32; ++s)
                if (s * 64 + lane == cand) v[s] = -1e30f;
            if (lane == 0) { s_ti[k] = cand; s_tt[k] = tanhf(m * rnorm); }
        }
    }
    __syncthreads();
    const float* h = W + OFF_H;
    const int o = blockIdx.x;
    for (int l = tid; l < 256; l += 256) {
        float sum = 0.f;
        if (l < L1LEN) {
            sum = c1b[o];
            sum += (c1w[o * 24 + 0] + c1w[o * 24 + 1]) * bn1b[0];
            sum += (c1w[o * 24 + 2] + c1w[o * 24 + 3]) * bn1b[1];
#pragma unroll
            for (int r = 0; r < KTOP; ++r) {
                int ch = r + 2;
                float tv = s_tt[r];
                float sr = BN_INV * bn1g[ch];
                float br = bn1b[ch];
                const float* hr = h + s_ti[r] * DD;
                float v0 = fmaf(hr[l], tv * sr, br);
                float v1 = fmaf(hr[l + 1], tv * sr, br);
                sum += c1w[o * 24 + ch * 2] * v0 + c1w[o * 24 + ch * 2 + 1] * v1;
            }
        }
        W[OFF_C1Q + o * 256 + l] = sum;   // l' = 255 padded 0
    }
}

// ---------------- k_edges: zero-LDS pipeline; all conv stages via v_dot2_f32_f16 ----------------
__launch_bounds__(256, 8)
__global__ void k_edges(const float* __restrict__ h, const int* __restrict__ te,
                        const float* __restrict__ W, float* __restrict__ out) {
    const int tid = threadIdx.x;
    const int w = tid >> 6, lane = tid & 63;
    const int e = blockIdx.x * 4 + w;

    int na = __builtin_amdgcn_readfirstlane(te[2 * e]);
    int nb = __builtin_amdgcn_readfirstlane(te[2 * e + 1]);
    const float* ha = h + na * DD;
    const float* hb = h + nb * DD;
    const float4* c1q = (const float4*)(W + OFF_C1Q);   // [12][64]
    const float2* v1p = (const float2*)(W + OFF_V1P);   // [12][64]
    const h2* wah = (const h2*)(W + OFF_WAH);           // [12]
    const h2* wbh = (const h2*)(W + OFF_WBH);           // [12]
    const h2* w2h = (const h2*)(W + OFF_W2H);           // [12][12]
    const h2* w3h = (const h2*)(W + OFF_W3H);           // [12][12] (i-major)
    const float* b2 = W + OFF_B2F;
    const float* b3 = W + OFF_B3F;
    const float4* v3t = (const float4*)(W + OFF_V3T);   // [32][3]

    float dot0 = 0.f, dot1 = 0.f;

    // ---- stage 1: fdot2; lane l computes pooled s1 at positions 2l (rA) and 2l+1 (rB) ----
    float rA[CC], rB[CC];
    {
        float4 a4 = *(const float4*)(ha + 4 * lane);
        float4 b4 = *(const float4*)(hb + 4 * lane);
        float ha4 = __shfl_down(a4.x, 1, 64);
        float hb4 = __shfl_down(b4.x, 1, 64);
        h2 pa01 = __builtin_amdgcn_cvt_pkrtz(a4.x, a4.y);
        h2 pa12 = __builtin_amdgcn_cvt_pkrtz(a4.y, a4.z);
        h2 pa23 = __builtin_amdgcn_cvt_pkrtz(a4.z, a4.w);
        h2 pa34 = __builtin_amdgcn_cvt_pkrtz(a4.w, ha4);
        h2 pb01 = __builtin_amdgcn_cvt_pkrtz(b4.x, b4.y);
        h2 pb12 = __builtin_amdgcn_cvt_pkrtz(b4.y, b4.z);
        h2 pb23 = __builtin_amdgcn_cvt_pkrtz(b4.z, b4.w);
        h2 pb34 = __builtin_amdgcn_cvt_pkrtz(b4.w, hb4);
#pragma unroll
        for (int o = 0; o < CC; ++o) {
            float4 c = c1q[o * 64 + lane];
            float2 vp = v1p[o * 64 + lane];
            h2 wva = wah[o], wvb = wbh[o];
            float u0 = __builtin_amdgcn_fdot2(pa01, wva, __builtin_amdgcn_fdot2(pb01, wvb, c.x, false), false);
            float u1 = __builtin_amdgcn_fdot2(pa12, wva, __builtin_amdgcn_fdot2(pb12, wvb, c.y, false), false);
            float u2 = __builtin_amdgcn_fdot2(pa23, wva, __builtin_amdgcn_fdot2(pb23, wvb, c.z, false), false);
            float u3 = __builtin_amdgcn_fdot2(pa34, wva, __builtin_amdgcn_fdot2(pb34, wvb, c.w, false), false);
            float ra = fmaxf(fmaxf(u0, u1), 0.0f);
            float rb = fmaxf(fmaxf(u2, u3), 0.0f);
            rA[o] = ra; rB[o] = rb;
            dot0 = fmaf(ra, vp.x, dot0);
            dot1 = fmaf(rb, vp.y, dot1);   // lane 63: vp.y == 0 (pad) kills garbage
        }
    }

    // ---- stage 2: fdot2 ----
    float r2[CC];
#pragma unroll
    for (int i = 0; i < CC; ++i) r2[i] = 0.f;
    {
        h2 pe[CC], po[CC];
#pragma unroll
        for (int i = 0; i < CC; ++i) {
            float ve1 = __shfl_down(rA[i], 1, 64);
            pe[i] = __builtin_amdgcn_cvt_pkrtz(rA[i], rB[i]);
            po[i] = __builtin_amdgcn_cvt_pkrtz(rB[i], ve1);
        }
        if (lane < P2LEN) {
            const float4* vrow = (const float4*)(W + OFF_V2T) + lane * 3;
#pragma unroll
            for (int g = 0; g < 3; ++g) {
                float4 q = vrow[g];
#pragma unroll
                for (int oo = 0; oo < 4; ++oo) {
                    const int o = g * 4 + oo;
                    float a0 = b2[o], a1 = b2[o];
#pragma unroll
                    for (int i = 0; i < CC; ++i) {
                        h2 wv = w2h[o * 12 + i];
                        a0 = __builtin_amdgcn_fdot2(pe[i], wv, a0, false);
                        a1 = __builtin_amdgcn_fdot2(po[i], wv, a1, false);
                    }
                    float r = fmaxf(fmaxf(a0, a1), 0.0f);
                    r2[o] = r;
                    float vv = (oo == 0) ? q.x : (oo == 1) ? q.y : (oo == 2) ? q.z : q.w;
                    if (o & 1) dot1 = fmaf(r, vv, dot1);
                    else       dot0 = fmaf(r, vv, dot0);
                }
            }
        }
    }

    // ---- stage 3: fdot2 with (t0,t1)-paired weights; shfl pooling ----
    {
        h2 pr[CC];
#pragma unroll
        for (int i = 0; i < CC; ++i) {
            float vq1 = __shfl_down(r2[i], 1, 64);
            pr[i] = __builtin_amdgcn_cvt_pkrtz(r2[i], vq1);
        }
        bool take = ((lane & 1) == 0) && (lane < 62);
        int t = lane >> 1;
        float4 ug0 = v3t[t * 3 + 0], ug1 = v3t[t * 3 + 1], ug2 = v3t[t * 3 + 2];
#pragma unroll
        for (int o = 0; o < CC; ++o) {
            float a = b3[o];
#pragma unroll
            for (int i = 0; i < CC; ++i)
                a = __builtin_amdgcn_fdot2(pr[i], w3h[i * 12 + o], a, false);
            float pn = __shfl_xor(a, 1, 64);
            float r = fmaxf(fmaxf(a, pn), 0.0f);
            if (take) {
                float wsel = (o < 4) ? ((o == 0) ? ug0.x : (o == 1) ? ug0.y : (o == 2) ? ug0.z : ug0.w)
                           : (o < 8) ? ((o == 4) ? ug1.x : (o == 5) ? ug1.y : (o == 6) ? ug1.z : ug1.w)
                                     : ((o == 8) ? ug2.x : (o == 9) ? ug2.y : (o == 10) ? ug2.z : ug2.w);
                if (o & 1) dot1 = fmaf(r, wsel, dot1);
                else       dot0 = fmaf(r, wsel, dot0);
            }
        }
    }

    // ---- wave reduce + sigmoid ----
    float dot = dot0 + dot1;
#pragma unroll
    for (int off = 32; off > 0; off >>= 1) dot += __shfl_xor(dot, off, 64);
    if (lane == 0) {
        float tt = dot + W[OFF_C0];
        out[e] = 1.0f / (1.0f + expf(-tt));
    }
}

extern "C" void kernel_launch(void* const* d_in, const int* in_sizes, int n_in,
                              void* d_out, int out_size, void* d_ws, size_t ws_size,
                              hipStream_t stream) {
    const float* x    = (const float*)d_in[0];
    const int*   ei   = (const int*)d_in[1];
    const int*   te   = (const int*)d_in[2];
    const float* Wl   = (const float*)d_in[3];
    const float* bl   = (const float*)d_in[4];
    const float* Wr   = (const float*)d_in[5];
    const float* tw   = (const float*)d_in[6];
    const float* c1w  = (const float*)d_in[7];
    const float* c1b  = (const float*)d_in[8];
    const float* c2w  = (const float*)d_in[9];
    const float* c2b  = (const float*)d_in[10];
    const float* c3w  = (const float*)d_in[11];
    const float* c3b  = (const float*)d_in[12];
    const float* bn1g = (const float*)d_in[13];
    const float* bn1b = (const float*)d_in[14];
    const float* bn2g = (const float*)d_in[15];
    const float* bn2b = (const float*)d_in[16];
    const float* bn3g = (const float*)d_in[17];
    const float* bn3b = (const float*)d_in[18];
    const float* bn4g = (const float*)d_in[19];
    const float* bn4b = (const float*)d_in[20];
    const float* fc1w = (const float*)d_in[21];
    const float* fc1b = (const float*)d_in[22];
    const float* fc2w = (const float*)d_in[23];
    const float* fc2b = (const float*)d_in[24];
    float* W   = (float*)d_ws;
    float* out = (float*)d_out;

    hipMemsetAsync(W + OFF_SC, 0, 4000 * sizeof(float), stream);
    k_fill<<<766, 256, 0, stream>>>(ei, x, Wr, fc1w, fc1b, fc2w, fc2b, bn4g, bn4b, c1w,
                                    c2w, c2b, c3w, c3b, bn1g, bn2g, bn2b, bn3g, bn3b, W);
    k_gather<<<N_NODES, 256, 0, stream>>>(x, W);
    dim3 g2(8, 63);
    k_sage<<<g2, 256, 0, stream>>>(Wl, bl, tw, W);
    k_topk<<<12, 256, 0, stream>>>(tw, c1w, c1b, bn1g, bn1b, W);
    k_edges<<<ET / 4, 256, 0, stream>>>(W + OFF_H, te, W, out);
}

// Round 18
// 135.802 us; speedup vs baseline: 1.0252x; 1.0252x over previous
//
#include <hip/hip_runtime.h>
#include <hip/hip_bf16.h>
#include <math.h>

#define N_NODES 2000
#define DIN 256
#define DD 256
#define KTOP 10
#define CC 12
#define EG 64000
#define ET 50000
#define L1LEN 255
#define P1LEN 127
#define P2LEN 63
#define P3LEN 31
#define FLAT 2652
#define BN_INV 0.9999950000375f
#define CAP 96

typedef float v2 __attribute__((ext_vector_type(2)));
typedef __fp16 h2 __attribute__((ext_vector_type(2)));

__device__ __forceinline__ v2 v2fma(v2 a, v2 b, v2 c) {
#if __has_builtin(__builtin_elementwise_fma)
    return __builtin_elementwise_fma(a, b, c);
#else
    v2 r; r.x = fmaf(a.x, b.x, c.x); r.y = fmaf(a.y, b.y, c.y); return r;
#endif
}
__device__ __forceinline__ v2 sp(float s) { v2 r; r.x = s; r.y = s; return r; }

// ---- workspace layout (float offsets) ----
#define OFF_MEAN   0                          // 512000
#define OFF_H      512000                     // 512000
#define OFF_SC     1024000                    // 2000 (zeroed by memset)
#define OFF_CNT    1026000                    // 2000 ints (zeroed by memset)
#define OFF_NBR    1028000                    // 2000*96 ints
#define OFF_TAB    1220000
#define OFF_C1Q    (OFF_TAB)                  // [12][256] pre-pool conv1 const (l'=255 pad 0)
#define OFF_V1P    (OFF_TAB + 3072)           // [12][128] dot weights for s1 (k=127 pad 0)
#define OFF_B2F    (OFF_TAB + 4944)           // 12
#define OFF_B3F    (OFF_TAB + 5244)           // 12
#define OFF_V2T    (OFF_TAB + 5256)           // [64][12]
#define OFF_V3T    (OFF_TAB + 6024)           // [32][12]
#define OFF_C0     (OFF_TAB + 6408)           // 1
#define OFF_W2H    (OFF_TAB + 6412)           // [o][i] h2 = 144 dwords
#define OFF_WAH    (OFF_TAB + 6556)           // [o] h2 = 12
#define OFF_WBH    (OFF_TAB + 6568)           // [o] h2 = 12
#define OFF_W3H    (OFF_TAB + 6580)           // [i][o] h2 = 144

// ---------------- k_fill: bucket fill (0-249) + v-split (250-260) + fold (261) + xWr GEMM (262-765) ----------------
__global__ void k_fill(const int* __restrict__ ei, const float* __restrict__ x,
                       const float* __restrict__ Wr,
                       const float* __restrict__ fc1w, const float* __restrict__ fc1b,
                       const float* __restrict__ fc2w, const float* __restrict__ fc2b,
                       const float* __restrict__ bn4g, const float* __restrict__ bn4b,
                       const float* __restrict__ c1w,
                       const float* __restrict__ c2w, const float* __restrict__ c2b,
                       const float* __restrict__ c3w, const float* __restrict__ c3b,
                       const float* __restrict__ bn1g,
                       const float* __restrict__ bn2g, const float* __restrict__ bn2b,
                       const float* __restrict__ bn3g, const float* __restrict__ bn3b,
                       float* __restrict__ W) {
    __shared__ float Xs[32][33], Brs[32][33];
    const int tid = threadIdx.x, bid = blockIdx.x;
    if (bid < 250) {
        int e = bid * 256 + tid;
        int* cnt = (int*)(W + OFF_CNT);
        int* nbr = (int*)(W + OFF_NBR);
        int dst = ei[EG + e], src = ei[e];
        int slot = atomicAdd(&cnt[dst], 1);
        nbr[dst * CAP + slot] = src;
        return;
    }
    if (bid < 261) {  // v = fc1_w^T (fc2_w * BN_INV * bn4_g) split into V1P / V2T / V3T
        int j = (bid - 250) * 256 + tid;
        if (j >= FLAT) return;
        float acc = 0.f;
        for (int k = 0; k < 128; ++k)
            acc += fc1w[k * FLAT + j] * (fc2w[k] * (BN_INV * bn4g[k]));
        int c = j / 221, pos = j - c * 221;
        if (pos < 127)      W[OFF_V1P + c * 128 + pos] = acc;
        else if (pos < 190) W[OFF_V2T + (pos - 127) * 12 + c] = acc;
        else                W[OFF_V3T + (pos - 190) * 12 + c] = acc;
        return;
    }
    if (bid == 261) {  // fold BN into conv weights (h2 tables) + pads
        if (tid < 144) {
            int o = tid / 12, i = tid - o * 12;
            float s2 = BN_INV * bn2g[i];
            ((h2*)(W + OFF_W2H))[o * 12 + i] =
                __builtin_amdgcn_cvt_pkrtz(c2w[o * 24 + i * 2] * s2, c2w[o * 24 + i * 2 + 1] * s2);
            float s3 = BN_INV * bn3g[i];
            ((h2*)(W + OFF_W3H))[i * 12 + o] =
                __builtin_amdgcn_cvt_pkrtz(c3w[o * 24 + i * 2] * s3, c3w[o * 24 + i * 2 + 1] * s3);
        }
        if (tid < 12) {
            float s2 = c2b[tid], s3 = c3b[tid];
            for (int i = 0; i < 12; ++i) {
                s2 += (c2w[tid * 24 + i * 2] + c2w[tid * 24 + i * 2 + 1]) * bn2b[i];
                s3 += (c3w[tid * 24 + i * 2] + c3w[tid * 24 + i * 2 + 1]) * bn3b[i];
            }
            W[OFF_B2F + tid] = s2;
            W[OFF_B3F + tid] = s3;
            W[OFF_V1P + tid * 128 + 127] = 0.f;   // pad: lane-63 rB dot weight
            float g0 = BN_INV * bn1g[0], g1 = BN_INV * bn1g[1];
            ((h2*)(W + OFF_WAH))[tid] =
                __builtin_amdgcn_cvt_pkrtz(c1w[tid * 24 + 0] * g0, c1w[tid * 24 + 1] * g0);
            ((h2*)(W + OFF_WBH))[tid] =
                __builtin_amdgcn_cvt_pkrtz(c1w[tid * 24 + 2] * g1, c1w[tid * 24 + 3] * g1);
        }
        if (tid == 0) {
            float c = fc2b[0];
            for (int k = 0; k < 128; ++k)
                c += fc2w[k] * (fc1b[k] * (BN_INV * bn4g[k]) + bn4b[k]);
            W[OFF_C0] = c;
        }
        return;
    }
    // ---- blocks 262..765: hpre = x @ Wr^T into OFF_H (no bias/relu) ----
    {
        int id = bid - 262;
        int bx = id & 7, by = id >> 3;
        int n0 = by * 32, d0 = bx * 32;
        int tx = tid & 15, ty = tid >> 4;
        int lrow = tid >> 3, lcol = (tid & 7) * 4;
        v2 acc0 = sp(0.f), acc1 = sp(0.f);
        for (int k0 = 0; k0 < DIN; k0 += 32) {
            int gn = n0 + lrow;
            float4 xv = (gn < N_NODES) ? *(const float4*)(x + gn * DIN + k0 + lcol)
                                       : make_float4(0.f, 0.f, 0.f, 0.f);
            Xs[lrow][lcol + 0] = xv.x; Xs[lrow][lcol + 1] = xv.y;
            Xs[lrow][lcol + 2] = xv.z; Xs[lrow][lcol + 3] = xv.w;
            float4 rv = *(const float4*)(Wr + (d0 + lrow) * DIN + k0 + lcol);
            Brs[lrow][lcol + 0] = rv.x; Brs[lrow][lcol + 1] = rv.y;
            Brs[lrow][lcol + 2] = rv.z; Brs[lrow][lcol + 3] = rv.w;
            __syncthreads();
#pragma unroll
            for (int kk = 0; kk < 32; ++kk) {
                v2 r; r.x = Brs[2 * tx][kk]; r.y = Brs[2 * tx + 1][kk];
                acc0 = v2fma(r, sp(Xs[2 * ty][kk]), acc0);
                acc1 = v2fma(r, sp(Xs[2 * ty + 1][kk]), acc1);
            }
            __syncthreads();
        }
        float* h = W + OFF_H;
#pragma unroll
        for (int i = 0; i < 2; ++i) {
            int n = n0 + 2 * ty + i;
            if (n < N_NODES) {
                v2 a = (i == 0) ? acc0 : acc1;
                h[n * DD + d0 + 2 * tx] = a.x;
                h[n * DD + d0 + 2 * tx + 1] = a.y;
            }
        }
    }
}

// ---------------- k_gather: 2 waves per node (feature halves), mean over bucket ----------------
__global__ void k_gather(const float* __restrict__ x, float* __restrict__ W) {
    int w = threadIdx.x >> 6, lane = threadIdx.x & 63;
    int n = blockIdx.x * 2 + (w >> 1);
    int fo = (w & 1) * 128 + lane * 2;
    const int* cnt = (const int*)(W + OFF_CNT);
    const int* nbr = (const int*)(W + OFF_NBR);
    int dg = cnt[n];
    const int* row = nbr + n * CAP;
    float ax = 0.f, ay = 0.f;
    int j = 0;
    for (; j + 4 <= dg; j += 4) {
        int s0 = row[j], s1 = row[j + 1], s2 = row[j + 2], s3 = row[j + 3];
        float2 v0 = *(const float2*)(x + s0 * DIN + fo);
        float2 v1 = *(const float2*)(x + s1 * DIN + fo);
        float2 v2_ = *(const float2*)(x + s2 * DIN + fo);
        float2 v3 = *(const float2*)(x + s3 * DIN + fo);
        ax += v0.x + v1.x + v2_.x + v3.x;
        ay += v0.y + v1.y + v2_.y + v3.y;
    }
    for (; j < dg; ++j) {
        int s0 = row[j];
        float2 v0 = *(const float2*)(x + s0 * DIN + fo);
        ax += v0.x; ay += v0.y;
    }
    float rd = 1.0f / fmaxf((float)dg, 1.0f);
    float2 o2; o2.x = ax * rd; o2.y = ay * rd;
    *(float2*)(W + OFF_MEAN + n * DIN + fo) = o2;
}

// ---------------- k_sage: h = relu(mean @ Wl^T + bl + hpre), fused score atomics ----------------
__global__ void k_sage(const float* __restrict__ Wl, const float* __restrict__ bl,
                       const float* __restrict__ tw, float* __restrict__ W) {
    __shared__ float As[32][33], Bls[32][33];
    const float* mean = W + OFF_MEAN;
    float* h = W + OFF_H;
    float* sc = W + OFF_SC;
    int tid = threadIdx.x;
    int tx = tid & 15, ty = tid >> 4;
    int n0 = blockIdx.y * 32, d0 = blockIdx.x * 32;
    int lrow = tid >> 3, lcol = (tid & 7) * 4;
    v2 acc0 = sp(0.f), acc1 = sp(0.f);
    for (int k0 = 0; k0 < DIN; k0 += 32) {
        int gn = n0 + lrow;
        float4 av = (gn < N_NODES) ? *(const float4*)(mean + gn * DIN + k0 + lcol)
                                   : make_float4(0.f, 0.f, 0.f, 0.f);
        As[lrow][lcol + 0] = av.x; As[lrow][lcol + 1] = av.y;
        As[lrow][lcol + 2] = av.z; As[lrow][lcol + 3] = av.w;
        float4 bv = *(const float4*)(Wl + (d0 + lrow) * DIN + k0 + lcol);
        Bls[lrow][lcol + 0] = bv.x; Bls[lrow][lcol + 1] = bv.y;
        Bls[lrow][lcol + 2] = bv.z; Bls[lrow][lcol + 3] = bv.w;
        __syncthreads();
#pragma unroll
        for (int kk = 0; kk < 32; ++kk) {
            v2 b; b.x = Bls[2 * tx][kk]; b.y = Bls[2 * tx + 1][kk];
            acc0 = v2fma(b, sp(As[2 * ty][kk]), acc0);
            acc1 = v2fma(b, sp(As[2 * ty + 1][kk]), acc1);
        }
        __syncthreads();
    }
    float tw0 = tw[d0 + 2 * tx], tw1 = tw[d0 + 2 * tx + 1];
    float bl0 = bl[d0 + 2 * tx], bl1 = bl[d0 + 2 * tx + 1];
    float s0 = 0.f, s1 = 0.f;
#pragma unroll
    for (int i = 0; i < 2; ++i) {
        int n = n0 + 2 * ty + i;
        if (n < N_NODES) {
            v2 a = (i == 0) ? acc0 : acc1;
            float h0 = fmaxf(a.x + bl0 + h[n * DD + d0 + 2 * tx], 0.f);
            float h1 = fmaxf(a.y + bl1 + h[n * DD + d0 + 2 * tx + 1], 0.f);
            h[n * DD + d0 + 2 * tx] = h0;
            h[n * DD + d0 + 2 * tx + 1] = h1;
            float s = fmaf(h0, tw0, h1 * tw1);
            if (i == 0) s0 = s; else s1 = s;
        }
    }
#pragma unroll
    for (int off = 8; off > 0; off >>= 1) {
        s0 += __shfl_xor(s0, off, 64);
        s1 += __shfl_xor(s1, off, 64);
    }
    if (tx == 0) {
        int n = n0 + 2 * ty;
        if (n < N_NODES) atomicAdd(&sc[n], s0);
        if (n + 1 < N_NODES) atomicAdd(&sc[n + 1], s1);
    }
}

// ---------------- k_topk: 12 blocks; wave-topk + one channel of pre-pool const C1Q ----------------
__global__ void k_topk(const float* __restrict__ tw, const float* __restrict__ c1w,
                       const float* __restrict__ c1b, const float* __restrict__ bn1g,
                       const float* __restrict__ bn1b, float* __restrict__ W) {
    __shared__ float s_tt[KTOP];
    __shared__ int   s_ti[KTOP];
    int tid = threadIdx.x;
    if (tid < 64) {
        int lane = tid;
        const float* sc = W + OFF_SC;
        float v[32];
#pragma unroll
        for (int s = 0; s < 32; ++s) {
            int idx = s * 64 + lane;
            v[s] = (idx < N_NODES) ? sc[idx] : -1e30f;
        }
        float p = 0.f;
#pragma unroll
        for (int k = 0; k < 4; ++k) { float t = tw[lane + 64 * k]; p = fmaf(t, t, p); }
#pragma unroll
        for (int off = 32; off > 0; off >>= 1) p += __shfl_xor(p, off, 64);
        float rnorm = 1.0f / sqrtf(p);
#pragma unroll
        for (int k = 0; k < KTOP; ++k) {
            float m = v[0];
#pragma unroll
            for (int s = 1; s < 32; ++s) m = fmaxf(m, v[s]);
#pragma unroll
            for (int off = 32; off > 0; off >>= 1) m = fmaxf(m, __shfl_xor(m, off, 64));
            int cand = 0x7fffffff;
#pragma unroll
            for (int s = 0; s < 32; ++s)
                if (v[s] == m) cand = min(cand, s * 64 + lane);
#pragma unroll
            for (int off = 32; off > 0; off >>= 1) cand = min(cand, __shfl_xor(cand, off, 64));
#pragma unroll
            for (int s = 0; s < 32; ++s)
                if (s * 64 + lane == cand) v[s] = -1e30f;
            if (lane == 0) { s_ti[k] = cand; s_tt[k] = tanhf(m * rnorm); }
        }
    }
    __syncthreads();
    const float* h = W + OFF_H;
    const int o = blockIdx.x;
    for (int l = tid; l < 256; l += 256) {
        float sum = 0.f;
        if (l < L1LEN) {
            sum = c1b[o];
            sum += (c1w[o * 24 + 0] + c1w[o * 24 + 1]) * bn1b[0];
            sum += (c1w[o * 24 + 2] + c1w[o * 24 + 3]) * bn1b[1];
#pragma unroll
            for (int r = 0; r < KTOP; ++r) {
                int ch = r + 2;
                float tv = s_tt[r];
                float sr = BN_INV * bn1g[ch];
                float br = bn1b[ch];
                const float* hr = h + s_ti[r] * DD;
                float v0 = fmaf(hr[l], tv * sr, br);
                float v1 = fmaf(hr[l + 1], tv * sr, br);
                sum += c1w[o * 24 + ch * 2] * v0 + c1w[o * 24 + ch * 2 + 1] * v1;
            }
        }
        W[OFF_C1Q + o * 256 + l] = sum;   // l' = 255 padded 0
    }
}

// ---------------- k_edges: zero-LDS pipeline; all conv stages via v_dot2_f32_f16 ----------------
__launch_bounds__(256, 7)
__global__ void k_edges(const float* __restrict__ h, const int* __restrict__ te,
                        const float* __restrict__ W, float* __restrict__ out) {
    const int tid = threadIdx.x;
    const int w = tid >> 6, lane = tid & 63;
    const int e = blockIdx.x * 4 + w;

    int na = __builtin_amdgcn_readfirstlane(te[2 * e]);
    int nb = __builtin_amdgcn_readfirstlane(te[2 * e + 1]);
    const float* ha = h + na * DD;
    const float* hb = h + nb * DD;
    const float4* c1q = (const float4*)(W + OFF_C1Q);   // [12][64]
    const float2* v1p = (const float2*)(W + OFF_V1P);   // [12][64]
    const h2* wah = (const h2*)(W + OFF_WAH);           // [12]
    const h2* wbh = (const h2*)(W + OFF_WBH);           // [12]
    const h2* w2h = (const h2*)(W + OFF_W2H);           // [12][12]
    const h2* w3h = (const h2*)(W + OFF_W3H);           // [12][12] (i-major)
    const float* b2 = W + OFF_B2F;
    const float* b3 = W + OFF_B3F;
    const float4* v3t = (const float4*)(W + OFF_V3T);   // [32][3]

    float dot0 = 0.f, dot1 = 0.f;

    // ---- stage 1: fdot2; lane l computes pooled s1 at positions 2l (rA) and 2l+1 (rB) ----
    float rA[CC], rB[CC];
    {
        float4 a4 = *(const float4*)(ha + 4 * lane);
        float4 b4 = *(const float4*)(hb + 4 * lane);
        float ha4 = __shfl_down(a4.x, 1, 64);
        float hb4 = __shfl_down(b4.x, 1, 64);
        h2 pa01 = __builtin_amdgcn_cvt_pkrtz(a4.x, a4.y);
        h2 pa12 = __builtin_amdgcn_cvt_pkrtz(a4.y, a4.z);
        h2 pa23 = __builtin_amdgcn_cvt_pkrtz(a4.z, a4.w);
        h2 pa34 = __builtin_amdgcn_cvt_pkrtz(a4.w, ha4);
        h2 pb01 = __builtin_amdgcn_cvt_pkrtz(b4.x, b4.y);
        h2 pb12 = __builtin_amdgcn_cvt_pkrtz(b4.y, b4.z);
        h2 pb23 = __builtin_amdgcn_cvt_pkrtz(b4.z, b4.w);
        h2 pb34 = __builtin_amdgcn_cvt_pkrtz(b4.w, hb4);
#pragma unroll
        for (int o = 0; o < CC; ++o) {
            float4 c = c1q[o * 64 + lane];
            float2 vp = v1p[o * 64 + lane];
            h2 wva = wah[o], wvb = wbh[o];
            float u0 = __builtin_amdgcn_fdot2(pa01, wva, __builtin_amdgcn_fdot2(pb01, wvb, c.x, false), false);
            float u1 = __builtin_amdgcn_fdot2(pa12, wva, __builtin_amdgcn_fdot2(pb12, wvb, c.y, false), false);
            float u2 = __builtin_amdgcn_fdot2(pa23, wva, __builtin_amdgcn_fdot2(pb23, wvb, c.z, false), false);
            float u3 = __builtin_amdgcn_fdot2(pa34, wva, __builtin_amdgcn_fdot2(pb34, wvb, c.w, false), false);
            float ra = fmaxf(fmaxf(u0, u1), 0.0f);
            float rb = fmaxf(fmaxf(u2, u3), 0.0f);
            rA[o] = ra; rB[o] = rb;
            dot0 = fmaf(ra, vp.x, dot0);
            dot1 = fmaf(rb, vp.y, dot1);   // lane 63: vp.y == 0 (pad) kills garbage
        }
    }

    // ---- stage 2: fdot2 ----
    float r2[CC];
#pragma unroll
    for (int i = 0; i < CC; ++i) r2[i] = 0.f;
    {
        h2 pe[CC], po[CC];
#pragma unroll
        for (int i = 0; i < CC; ++i) {
            float ve1 = __shfl_down(rA[i], 1, 64);
            pe[i] = __builtin_amdgcn_cvt_pkrtz(rA[i], rB[i]);
            po[i] = __builtin_amdgcn_cvt_pkrtz(rB[i], ve1);
        }
        if (lane < P2LEN) {
            const float4* vrow = (const float4*)(W + OFF_V2T) + lane * 3;
#pragma unroll
            for (int g = 0; g < 3; ++g) {
                float4 q = vrow[g];
#pragma unroll
                for (int oo = 0; oo < 4; ++oo) {
                    const int o = g * 4 + oo;
                    float a0 = b2[o], a1 = b2[o];
#pragma unroll
                    for (int i = 0; i < CC; ++i) {
                        h2 wv = w2h[o * 12 + i];
                        a0 = __builtin_amdgcn_fdot2(pe[i], wv, a0, false);
                        a1 = __builtin_amdgcn_fdot2(po[i], wv, a1, false);
                    }
                    float r = fmaxf(fmaxf(a0, a1), 0.0f);
                    r2[o] = r;
                    float vv = (oo == 0) ? q.x : (oo == 1) ? q.y : (oo == 2) ? q.z : q.w;
                    if (o & 1) dot1 = fmaf(r, vv, dot1);
                    else       dot0 = fmaf(r, vv, dot0);
                }
            }
        }
    }

    // ---- stage 3: fdot2 with (t0,t1)-paired weights; shfl pooling ----
    {
        h2 pr[CC];
#pragma unroll
        for (int i = 0; i < CC; ++i) {
            float vq1 = __shfl_down(r2[i], 1, 64);
            pr[i] = __builtin_amdgcn_cvt_pkrtz(r2[i], vq1);
        }
        bool take = ((lane & 1) == 0) && (lane < 62);
        int t = lane >> 1;
        float4 ug0 = v3t[t * 3 + 0], ug1 = v3t[t * 3 + 1], ug2 = v3t[t * 3 + 2];
#pragma unroll
        for (int o = 0; o < CC; ++o) {
            float a = b3[o];
#pragma unroll
            for (int i = 0; i < CC; ++i)
                a = __builtin_amdgcn_fdot2(pr[i], w3h[i * 12 + o], a, false);
            float pn = __shfl_xor(a, 1, 64);
            float r = fmaxf(fmaxf(a, pn), 0.0f);
            if (take) {
                float wsel = (o < 4) ? ((o == 0) ? ug0.x : (o == 1) ? ug0.y : (o == 2) ? ug0.z : ug0.w)
                           : (o < 8) ? ((o == 4) ? ug1.x : (o == 5) ? ug1.y : (o == 6) ? ug1.z : ug1.w)
                                     : ((o == 8) ? ug2.x : (o == 9) ? ug2.y : (o == 10) ? ug2.z : ug2.w);
                if (o & 1) dot1 = fmaf(r, wsel, dot1);
                else       dot0 = fmaf(r, wsel, dot0);
            }
        }
    }

    // ---- wave reduce + sigmoid ----
    float dot = dot0 + dot1;
#pragma unroll
    for (int off = 32; off > 0; off >>= 1) dot += __shfl_xor(dot, off, 64);
    if (lane == 0) {
        float tt = dot + W[OFF_C0];
        out[e] = 1.0f / (1.0f + expf(-tt));
    }
}

extern "C" void kernel_launch(void* const* d_in, const int* in_sizes, int n_in,
                              void* d_out, int out_size, void* d_ws, size_t ws_size,
                              hipStream_t stream) {
    const float* x    = (const float*)d_in[0];
    const int*   ei   = (const int*)d_in[1];
    const int*   te   = (const int*)d_in[2];
    const float* Wl   = (const float*)d_in[3];
    const float* bl   = (const float*)d_in[4];
    const float* Wr   = (const float*)d_in[5];
    const float* tw   = (const float*)d_in[6];
    const float* c1w  = (const float*)d_in[7];
    const float* c1b  = (const float*)d_in[8];
    const float* c2w  = (const float*)d_in[9];
    const float* c2b  = (const float*)d_in[10];
    const float* c3w  = (const float*)d_in[11];
    const float* c3b  = (const float*)d_in[12];
    const float* bn1g = (const float*)d_in[13];
    const float* bn1b = (const float*)d_in[14];
    const float* bn2g = (const float*)d_in[15];
    const float* bn2b = (const float*)d_in[16];
    const float* bn3g = (const float*)d_in[17];
    const float* bn3b = (const float*)d_in[18];
    const float* bn4g = (const float*)d_in[19];
    const float* bn4b = (const float*)d_in[20];
    const float* fc1w = (const float*)d_in[21];
    const float* fc1b = (const float*)d_in[22];
    const float* fc2w = (const float*)d_in[23];
    const float* fc2b = (const float*)d_in[24];
    float* W   = (float*)d_ws;
    float* out = (float*)d_out;

    hipMemsetAsync(W + OFF_SC, 0, 4000 * sizeof(float), stream);
    k_fill<<<766, 256, 0, stream>>>(ei, x, Wr, fc1w, fc1b, fc2w, fc2b, bn4g, bn4b, c1w,
                                    c2w, c2b, c3w, c3b, bn1g, bn2g, bn2b, bn3g, bn3b, W);
    k_gather<<<1000, 256, 0, stream>>>(x, W);
    dim3 g2(8, 63);
    k_sage<<<g2, 256, 0, stream>>>(Wl, bl, tw, W);
    k_topk<<<12, 256, 0, stream>>>(tw, c1w, c1b, bn1g, bn1b, W);
    k_edges<<<ET / 4, 256, 0, stream>>>(W + OFF_H, te, W, out);
}